// Round 4
// baseline (72.861 us; speedup 1.0000x reference)
//
#include <hip/hip_runtime.h>
#include <cstdint>
#include <cmath>

#define HIDDEN   768
#define NPAIR    (HIDDEN / 2)      // 384 (sin,cos) pairs per row
#define SEQ_N    4096
#define LN_EPS   1e-12f
#define N_HI     80                // angle = 64*hi*d_i, hi in [0,80)
#define N_LO     64                // angle = lo*d_i,    lo in [0,64)

typedef float f4v __attribute__((ext_vector_type(4)));

// ---------------------------------------------------------------------------
// Kernel 1: build the two compact angle-addition tables in d_ws.
//   T1[hi][i] = (sin, cos)(64*hi * d_i)   hi in [0,80)
//   T2[lo][i] = (sin, cos)(lo    * d_i)   lo in [0,64)
// d_i = exp(-2i * ln(10000)/HIDDEN).  pe[p] reconstructed exactly via
// sin(A+B)/cos(A+B) with p = 64*hi + lo.  Tables = 442 KB -> L2-resident.
// ---------------------------------------------------------------------------
__global__ __launch_bounds__(256) void pe_tables_kernel(float2* __restrict__ t1,
                                                        float2* __restrict__ t2) {
    const int total = (N_HI + N_LO) * NPAIR;
    int idx = blockIdx.x * blockDim.x + threadIdx.x;
    if (idx >= total) return;
    int r = idx / NPAIR;
    int i = idx % NPAIR;
    const float L = logf(10000.0f) / (float)HIDDEN;
    float div = expf(-2.0f * (float)i * L);
    float s, c;
    if (r < N_HI) {
        sincosf((float)(r * 64) * div, &s, &c);
        t1[(size_t)r * NPAIR + i] = make_float2(s, c);
    } else {
        int lo = r - N_HI;
        sincosf((float)lo * div, &s, &c);
        t2[(size_t)lo * NPAIR + i] = make_float2(s, c);
    }
}

// sin(A+B) = sA*cB + cA*sB ; cos(A+B) = cA*cB - sA*sB
// a = (sinA0, cosA0, sinA1, cosA1), b = (sinB0, cosB0, sinB1, cosB1)
__device__ __forceinline__ void pe_acc(float4& acc, const float4 a, const float4 b) {
    acc.x += a.x * b.y + a.y * b.x;
    acc.y += a.y * b.y - a.x * b.x;
    acc.z += a.z * b.w + a.w * b.z;
    acc.w += a.w * b.w - a.z * b.z;
}

// ---------------------------------------------------------------------------
// Kernel 2: fused embedding-sum + LayerNorm.  TWO tokens per 64-lane wave,
// fully interleaved, so ~20 independent float4 gathers are in flight per
// round (latency hiding).  Output uses non-temporal stores so the 98 MB
// write stream does not evict the word-embedding table from L3.
// ---------------------------------------------------------------------------
__global__ __launch_bounds__(256) void emb_ln_kernel(
    const int*    __restrict__ ids,       // (B*N)
    const int*    __restrict__ svec,      // (B*N, 3)
    const int*    __restrict__ tt,        // (B*N)
    const float*  __restrict__ word_emb,  // (VOCAB, HIDDEN)
    const float*  __restrict__ type_emb,  // (2, HIDDEN)
    const float*  __restrict__ gamma,     // (HIDDEN)
    const float*  __restrict__ beta,      // (HIDDEN)
    const float2* __restrict__ t1,        // (N_HI, NPAIR) (sin,cos)
    const float2* __restrict__ t2,        // (N_LO, NPAIR) (sin,cos)
    float*        __restrict__ out,       // (B*N, HIDDEN)
    int n_tokens)
{
    const int wave = threadIdx.x >> 6;
    const int lane = threadIdx.x & 63;
    const int gw   = blockIdx.x * 4 + wave;   // global wave index
    const int tokA = gw * 2;
    if (tokA >= n_tokens) return;
    const bool hasB = (tokA + 1) < n_tokens;
    const int tokB = hasB ? tokA + 1 : tokA;

    // ---- wave-uniform index loads (both tokens up front) ----
    const int idA = ids[tokA],            idB = ids[tokB];
    const int tyA = tt[tokA],             tyB = tt[tokB];
    const int nA  = tokA & (SEQ_N - 1),   nB  = tokB & (SEQ_N - 1);
    const int a0A = svec[tokA * 3 + 0], a1A = svec[tokA * 3 + 1], a2A = svec[tokA * 3 + 2];
    const int a0B = svec[tokB * 3 + 0], a1B = svec[tokB * 3 + 1], a2B = svec[tokB * 3 + 2];

    const float4* wrowA = reinterpret_cast<const float4*>(word_emb + (size_t)idA * HIDDEN);
    const float4* wrowB = reinterpret_cast<const float4*>(word_emb + (size_t)idB * HIDDEN);
    const float4* trowA = reinterpret_cast<const float4*>(type_emb + (size_t)tyA * HIDDEN);
    const float4* trowB = reinterpret_cast<const float4*>(type_emb + (size_t)tyB * HIDDEN);

    #define T1ROW(p) reinterpret_cast<const float4*>(t1 + (size_t)((p) >> 6) * NPAIR)
    #define T2ROW(p) reinterpret_cast<const float4*>(t2 + (size_t)((p) & 63) * NPAIR)
    const float4* PA[8] = { T1ROW(nA), T2ROW(nA), T1ROW(a0A), T2ROW(a0A),
                            T1ROW(a1A), T2ROW(a1A), T1ROW(a2A), T2ROW(a2A) };
    const float4* PB[8] = { T1ROW(nB), T2ROW(nB), T1ROW(a0B), T2ROW(a0B),
                            T1ROW(a1B), T2ROW(a1B), T1ROW(a2B), T2ROW(a2B) };
    #undef T1ROW
    #undef T2ROW

    float4 accA[3], accB[3];
    float sA = 0.0f, ssA = 0.0f, sB = 0.0f, ssB = 0.0f;

    #pragma unroll
    for (int k = 0; k < 3; ++k) {
        const int d4 = lane + 64 * k;

        // ---- issue all 20 independent float4 gathers for this round ----
        float4 wA = wrowA[d4], tA = trowA[d4];
        float4 wB = wrowB[d4], tB = trowB[d4];
        float4 hA0 = PA[0][d4], lA0 = PA[1][d4], hA1 = PA[2][d4], lA1 = PA[3][d4];
        float4 hA2 = PA[4][d4], lA2 = PA[5][d4], hA3 = PA[6][d4], lA3 = PA[7][d4];
        float4 hB0 = PB[0][d4], lB0 = PB[1][d4], hB1 = PB[2][d4], lB1 = PB[3][d4];
        float4 hB2 = PB[4][d4], lB2 = PB[5][d4], hB3 = PB[6][d4], lB3 = PB[7][d4];

        float4 xA;
        xA.x = wA.x + tA.x; xA.y = wA.y + tA.y; xA.z = wA.z + tA.z; xA.w = wA.w + tA.w;
        pe_acc(xA, hA0, lA0); pe_acc(xA, hA1, lA1);
        pe_acc(xA, hA2, lA2); pe_acc(xA, hA3, lA3);

        float4 xB;
        xB.x = wB.x + tB.x; xB.y = wB.y + tB.y; xB.z = wB.z + tB.z; xB.w = wB.w + tB.w;
        pe_acc(xB, hB0, lB0); pe_acc(xB, hB1, lB1);
        pe_acc(xB, hB2, lB2); pe_acc(xB, hB3, lB3);

        accA[k] = xA;
        sA  += xA.x + xA.y + xA.z + xA.w;
        ssA += xA.x * xA.x + xA.y * xA.y + xA.z * xA.z + xA.w * xA.w;
        accB[k] = xB;
        sB  += xB.x + xB.y + xB.z + xB.w;
        ssB += xB.x * xB.x + xB.y * xB.y + xB.z * xB.z + xB.w * xB.w;
    }

    // ---- 64-lane butterfly reductions (independent, scheduler interleaves) ----
    #pragma unroll
    for (int off = 1; off < 64; off <<= 1) {
        sA  += __shfl_xor(sA,  off);
        ssA += __shfl_xor(ssA, off);
        sB  += __shfl_xor(sB,  off);
        ssB += __shfl_xor(ssB, off);
    }

    const float meanA = sA * (1.0f / (float)HIDDEN);
    const float varA  = ssA * (1.0f / (float)HIDDEN) - meanA * meanA;
    const float invA  = rsqrtf(varA + LN_EPS);
    const float meanB = sB * (1.0f / (float)HIDDEN);
    const float varB  = ssB * (1.0f / (float)HIDDEN) - meanB * meanB;
    const float invB  = rsqrtf(varB + LN_EPS);

    const float4* g4 = reinterpret_cast<const float4*>(gamma);
    const float4* b4 = reinterpret_cast<const float4*>(beta);
    f4v* orowA = reinterpret_cast<f4v*>(out + (size_t)tokA * HIDDEN);
    f4v* orowB = reinterpret_cast<f4v*>(out + (size_t)tokB * HIDDEN);

    #pragma unroll
    for (int k = 0; k < 3; ++k) {
        const int d4 = lane + 64 * k;
        const float4 g = g4[d4];
        const float4 b = b4[d4];
        {
            const float4 x = accA[k];
            f4v r;
            r.x = (x.x - meanA) * invA * g.x + b.x;
            r.y = (x.y - meanA) * invA * g.y + b.y;
            r.z = (x.z - meanA) * invA * g.z + b.z;
            r.w = (x.w - meanA) * invA * g.w + b.w;
            __builtin_nontemporal_store(r, &orowA[d4]);
        }
        if (hasB) {
            const float4 x = accB[k];
            f4v r;
            r.x = (x.x - meanB) * invB * g.x + b.x;
            r.y = (x.y - meanB) * invB * g.y + b.y;
            r.z = (x.z - meanB) * invB * g.z + b.z;
            r.w = (x.w - meanB) * invB * g.w + b.w;
            __builtin_nontemporal_store(r, &orowB[d4]);
        }
    }
}

extern "C" void kernel_launch(void* const* d_in, const int* in_sizes, int n_in,
                              void* d_out, int out_size, void* d_ws, size_t ws_size,
                              hipStream_t stream) {
    const int*   ids      = (const int*)d_in[0];   // input_ids      (B*N)
    const int*   svec     = (const int*)d_in[1];   // tok_struct_vec (B*N*3)
    const int*   tt       = (const int*)d_in[2];   // token_type_ids (B*N)
    const float* word_emb = (const float*)d_in[3]; // (VOCAB, HIDDEN)
    const float* type_emb = (const float*)d_in[4]; // (2, HIDDEN)
    const float* gamma    = (const float*)d_in[5]; // (HIDDEN)
    const float* beta     = (const float*)d_in[6]; // (HIDDEN)
    float*       out      = (float*)d_out;

    const int n_tokens = in_sizes[0];
    const int n_waves  = (n_tokens + 1) / 2;       // 2 tokens per wave
    const int grid_main = (n_waves + 3) / 4;       // 4 waves per block

    // Workspace layout: T1 (80x384 float2) | T2 (64x384 float2) = 442 KB.
    float2* t1 = (float2*)d_ws;
    float2* t2 = t1 + (size_t)N_HI * NPAIR;

    const int total_tab = (N_HI + N_LO) * NPAIR;
    pe_tables_kernel<<<(total_tab + 255) / 256, 256, 0, stream>>>(t1, t2);
    emb_ln_kernel<<<grid_main, 256, 0, stream>>>(
        ids, svec, tt, word_emb, type_emb, gamma, beta, t1, t2, out, n_tokens);
}